// Round 13
// baseline (138.337 us; speedup 1.0000x reference)
//
#include <hip/hip_runtime.h>
#include <hip/hip_bf16.h>

// NeighbourhoodAttnBlock: B=2, H=W=64, D=512, NH=8, DH=64, KERNEL=7
// Inputs fp32; output fp32. Internal pipeline bf16 MFMA.
// Stage 0: fused convert x, w_qkv, w_out fp32 -> bf16 in ws (1 launch)
// Stage 1: qkv GEMM (BK=64 dual-half LDS staging) -> q,k [bh][s][dh]; vt
// Stage 2: MFMA neighbourhood attention, 45 KB LDS (K/V staged in halves)
//          -> 3 blocks/CU
// Stage 3: out GEMM (BK=64, BN=64) -> d_out (fp32)

typedef __bf16 bf16x8 __attribute__((ext_vector_type(8)));
typedef __bf16 bf16x4 __attribute__((ext_vector_type(4)));
typedef float  f32x4  __attribute__((ext_vector_type(4)));

__global__ __launch_bounds__(256) void cvt_all(
    const float* __restrict__ x, const float* __restrict__ wq,
    const float* __restrict__ wo, __bf16* __restrict__ xb,
    __bf16* __restrict__ wqb, __bf16* __restrict__ wob) {
  int i = blockIdx.x * 256 + threadIdx.x;  // 1310720 total f32x4 chunks
  const float* src;
  __bf16* dst;
  int j = i;
  if (j < 1048576) {
    src = x; dst = xb;
  } else if (j < 1048576 + 196608) {
    j -= 1048576; src = wq; dst = wqb;
  } else {
    j -= 1048576 + 196608; src = wo; dst = wob;
  }
  f32x4 v = ((const f32x4*)src)[j];
  bf16x4 o;
  o[0] = (__bf16)v[0]; o[1] = (__bf16)v[1];
  o[2] = (__bf16)v[2]; o[3] = (__bf16)v[3];
  ((bf16x4*)dst)[j] = o;
}

__device__ __forceinline__ void gload_lds16(const __bf16* g, __bf16* l) {
  __builtin_amdgcn_global_load_lds(
      (const __attribute__((address_space(1))) void*)g,
      (__attribute__((address_space(3))) void*)l, 16, 0, 0);
}

// C[i][e] = sum_d A[i][d] * W[e][d];  A:[M,512], W:[E,512] row-major bf16.
// 128xBN block tile, 4 waves x (64 x BN/2). BK=64 via two contiguous 32-col
// half-buffers (global_load_lds needs unpadded contiguity).
template <bool QKV, int BN>
__global__ __launch_bounds__(256, 3) void gemm_lds(
    const __bf16* __restrict__ A, const __bf16* __restrict__ W,
    __bf16* __restrict__ qo, __bf16* __restrict__ ko, __bf16* __restrict__ vo,
    float* __restrict__ co, int etiles) {
  constexpr int K = 512;
  constexpr int NT = BN / 32;
  constexpr int WHALF = BN * 32;
  __shared__ alignas(16) __bf16 Al[2 * 128 * 32];
  __shared__ alignas(16) __bf16 Wl[2 * WHALF];
  const int tid = threadIdx.x;
  const int wv = tid >> 6, lane = tid & 63;
  const int n16 = lane & 15, quad = lane >> 4;
  const int bi = blockIdx.x / etiles, be = blockIdx.x % etiles;
  const int i0 = bi << 7, e0 = be * BN;
  const int wm = (wv & 1) << 6, we = (wv >> 1) * (BN / 2);

  const int srow = (wv << 4) + (lane >> 2);
  const int scol = (lane & 3) << 3;
  const __bf16* gA = A + (size_t)(i0 + srow) * K + scol;
  const __bf16* gW = W + (size_t)(e0 + srow) * K + scol;
  const int soff = (wv << 9) + (lane << 3);

  f32x4 acc[4][NT];
#pragma unroll
  for (int a = 0; a < 4; ++a)
#pragma unroll
    for (int b = 0; b < NT; ++b) acc[a][b] = (f32x4){0.f, 0.f, 0.f, 0.f};

  for (int k0 = 0; k0 < K; k0 += 64) {
    if (k0) __syncthreads();
#pragma unroll
    for (int h = 0; h < 2; ++h) {
      gload_lds16(gA + k0 + h * 32, &Al[h * 4096 + soff]);
      gload_lds16(gA + (size_t)64 * K + k0 + h * 32,
                  &Al[h * 4096 + 64 * 32 + soff]);
      gload_lds16(gW + k0 + h * 32, &Wl[h * WHALF + soff]);
      if (BN == 128)
        gload_lds16(gW + (size_t)64 * K + k0 + h * 32,
                    &Wl[h * WHALF + 64 * 32 + soff]);
    }
    __syncthreads();

#pragma unroll
    for (int h = 0; h < 2; ++h) {
      bf16x8 af[4], wf[NT];
#pragma unroll
      for (int t = 0; t < 4; ++t)
        af[t] = *(const bf16x8*)&Al[h * 4096 + (wm + t * 16 + n16) * 32 +
                                    quad * 8];
#pragma unroll
      for (int t = 0; t < NT; ++t)
        wf[t] = *(const bf16x8*)&Wl[h * WHALF + (we + t * 16 + n16) * 32 +
                                    quad * 8];
#pragma unroll
      for (int mt = 0; mt < 4; ++mt)
#pragma unroll
        for (int nt = 0; nt < NT; ++nt)
          acc[mt][nt] = __builtin_amdgcn_mfma_f32_16x16x32_bf16(
              af[mt], wf[nt], acc[mt][nt], 0, 0, 0);
    }
  }

#pragma unroll
  for (int mt = 0; mt < 4; ++mt)
#pragma unroll
    for (int nt = 0; nt < NT; ++nt) {
      f32x4 f = acc[mt][nt];
      int e = e0 + we + nt * 16 + n16;
#pragma unroll
      for (int rg = 0; rg < 4; ++rg) {
        int i = i0 + wm + mt * 16 + quad * 4 + rg;
        float val = f[rg];
        if (QKV) {
          int t = e >> 9, head = (e >> 6) & 7, dh = e & 63;
          int b = i >> 12, s = i & 4095;
          int bh = b * 8 + head;
          if (t == 2) {
            vo[((size_t)bh * 64 + dh) * 4096 + s] = (__bf16)val;  // vt[bh][dh][s]
          } else {
            size_t off = (((size_t)bh * 4096) + s) * 64 + dh;
            ((t == 0) ? qo : ko)[off] = (__bf16)val;
          }
        } else {
          co[(size_t)i * 512 + e] = val;  // fp32 output
        }
      }
    }
}

// MFMA neighbourhood attention, 45 KB LDS -> 3 blocks/CU (verified math,
// R10 phase-2). One workgroup per (bh, 8x8 query tile). K window loaded in
// two row-halves through r1 (16 KB); V window in two dh-halves through r1.
__global__ __launch_bounds__(256) void attn_mfma(
    const __bf16* __restrict__ q, const __bf16* __restrict__ k,
    const __bf16* __restrict__ vt, __bf16* __restrict__ out) {
  __shared__ alignas(16) __bf16 r1[8192];          // K-half / V-half buffer
  __shared__ alignas(16) __bf16 P[4][16][232];     // per-wave P (padded)
  const int tid = threadIdx.x;
  const int wv = tid >> 6;
  const int lane = tid & 63;
  const int n16 = lane & 15, quad = lane >> 4;
  const int bh = blockIdx.x >> 6;
  const int tile = blockIdx.x & 63;
  const int qh0 = (tile >> 3) << 3, qw0 = (tile & 7) << 3;
  int wh0 = qh0 - 3; wh0 = wh0 < 0 ? 0 : (wh0 > 50 ? 50 : wh0);
  int wc0 = qw0 - 3; wc0 = wc0 < 0 ? 0 : (wc0 > 48 ? 48 : wc0);
  wc0 &= ~1;  // -> multiple of 4; window covers [qw0-3, qw0+10]
  const size_t base = (size_t)bh * 4096 * 64;

  // ---- Q A-frags ----
  const int qi_a = wv * 16 + n16;
  const int sqa = (qh0 + (qi_a >> 3)) * 64 + qw0 + (qi_a & 7);
  const __bf16* qp = q + base + (size_t)sqa * 64 + quad * 8;
  bf16x8 aq0 = *(const bf16x8*)qp;
  bf16x8 aq1 = *(const bf16x8*)(qp + 32);

  const __bf16* kbase = k + base;
  const int skw = wc0 + n16;
  const int sw1 = ((quad ^ (n16 & 7)) * 8);
  const int sw2 = (((4 + quad) ^ (n16 & 7)) * 8);
  f32x4 S[14];

  // --- K half A: window rows 0..7 ---
#pragma unroll
  for (int i = 0; i < 4; ++i) {
    int ch = i * 256 + tid;
    int kr = ch >> 7, wi = ch & 127;
    int kc = wi >> 3, dh8 = wi & 7;
    bf16x8 d = *(const bf16x8*)(kbase +
        (size_t)((wh0 + kr) * 64 + wc0 + kc) * 64 + dh8 * 8);
    *(bf16x8*)&r1[(kr * 16 + kc) * 64 + ((dh8 ^ (kc & 7)) * 8)] = d;
  }
  __syncthreads();
#pragma unroll
  for (int nt = 0; nt < 8; ++nt) {
    int key = nt * 16 + n16;
    bf16x8 b0 = *(const bf16x8*)&r1[key * 64 + sw1];
    bf16x8 b1 = *(const bf16x8*)&r1[key * 64 + sw2];
    f32x4 s = {0.f, 0.f, 0.f, 0.f};
    s = __builtin_amdgcn_mfma_f32_16x16x32_bf16(aq0, b0, s, 0, 0, 0);
    s = __builtin_amdgcn_mfma_f32_16x16x32_bf16(aq1, b1, s, 0, 0, 0);
    S[nt] = s;
  }
  // --- K half B: window rows 8..13 ---
  __syncthreads();
#pragma unroll
  for (int i = 0; i < 3; ++i) {
    int ch = i * 256 + tid;
    int kr = ch >> 7, wi = ch & 127;  // kr 0..5 -> rows 8..13
    int kc = wi >> 3, dh8 = wi & 7;
    bf16x8 d = *(const bf16x8*)(kbase +
        (size_t)((wh0 + 8 + kr) * 64 + wc0 + kc) * 64 + dh8 * 8);
    *(bf16x8*)&r1[(kr * 16 + kc) * 64 + ((dh8 ^ (kc & 7)) * 8)] = d;
  }
  __syncthreads();
#pragma unroll
  for (int nt = 0; nt < 6; ++nt) {
    int key = nt * 16 + n16;
    bf16x8 b0 = *(const bf16x8*)&r1[key * 64 + sw1];
    bf16x8 b1 = *(const bf16x8*)&r1[key * 64 + sw2];
    f32x4 s = {0.f, 0.f, 0.f, 0.f};
    s = __builtin_amdgcn_mfma_f32_16x16x32_bf16(aq0, b0, s, 0, 0, 0);
    s = __builtin_amdgcn_mfma_f32_16x16x32_bf16(aq1, b1, s, 0, 0, 0);
    S[8 + nt] = s;
  }

  // ---- exact mask + scale + row max ----
  float mx[4] = {-1e30f, -1e30f, -1e30f, -1e30f};
#pragma unroll
  for (int reg = 0; reg < 4; ++reg) {
    int qi = wv * 16 + quad * 4 + reg;
    int qh = qh0 + (qi >> 3), qw = qw0 + (qi & 7);
    int sh = qh - 3; sh = sh < 0 ? 0 : (sh > 57 ? 57 : sh);
    int sw = qw - 3; sw = sw < 0 ? 0 : (sw > 57 ? 57 : sw);
    bool wok = (skw >= sw) && (skw < sw + 7);
#pragma unroll
    for (int nt = 0; nt < 14; ++nt) {
      int kh = wh0 + nt;
      bool ok = wok && (kh >= sh) && (kh < sh + 7);
      float val = ok ? S[nt][reg] * 0.125f : -1e30f;
      S[nt][reg] = val;
      mx[reg] = mx[reg] > val ? mx[reg] : val;
    }
  }
#pragma unroll
  for (int reg = 0; reg < 4; ++reg)
#pragma unroll
    for (int off = 8; off >= 1; off >>= 1) {
      float o = __shfl_xor(mx[reg], off);
      mx[reg] = mx[reg] > o ? mx[reg] : o;
    }

  // ---- exp + row sum ----
  float sm[4] = {0.f, 0.f, 0.f, 0.f};
#pragma unroll
  for (int nt = 0; nt < 14; ++nt)
#pragma unroll
    for (int reg = 0; reg < 4; ++reg) {
      float p = __expf(S[nt][reg] - mx[reg]);
      S[nt][reg] = p;
      sm[reg] += p;
    }
#pragma unroll
  for (int reg = 0; reg < 4; ++reg)
#pragma unroll
    for (int off = 8; off >= 1; off >>= 1) sm[reg] += __shfl_xor(sm[reg], off);

  // ---- P -> per-wave LDS region (wave-private) ----
#pragma unroll
  for (int reg = 0; reg < 4; ++reg) {
    float inv = 1.f / sm[reg];
    int row = quad * 4 + reg;
#pragma unroll
    for (int nt = 0; nt < 14; ++nt)
      P[wv][row][nt * 16 + n16] = (__bf16)(S[nt][reg] * inv);
  }

  // ---- PV in two dh-halves; V half = vwin[32][232] in r1 ----
  const __bf16* vbase = vt + base;
  f32x4 O[4];
#pragma unroll
  for (int h = 0; h < 2; ++h) {
    __syncthreads();  // prior r1 reads done
#pragma unroll
    for (int i = 0; i < 7; ++i) {
      int c = i * 256 + tid;          // 1792 8-B chunks
      int dh = c / 56, rem = c % 56;  // dh 0..31
      int kr = rem >> 2, qtr = rem & 3;
      bf16x4 d = *(const bf16x4*)(vbase + (size_t)(h * 32 + dh) * 4096 +
                                  (wh0 + kr) * 64 + wc0 + qtr * 4);
      *(bf16x4*)&r1[dh * 232 + kr * 16 + qtr * 4] = d;
    }
    __syncthreads();
#pragma unroll
    for (int ntv = 0; ntv < 2; ++ntv) {
      int oi = h * 2 + ntv;
      O[oi] = (f32x4){0.f, 0.f, 0.f, 0.f};
#pragma unroll
      for (int kt = 0; kt < 7; ++kt) {
        bf16x8 pa = *(const bf16x8*)&P[wv][n16][kt * 32 + quad * 8];
        bf16x8 vb = *(const bf16x8*)&r1[(ntv * 16 + n16) * 232 +
                                        kt * 32 + quad * 8];
        O[oi] = __builtin_amdgcn_mfma_f32_16x16x32_bf16(pa, vb, O[oi], 0, 0, 0);
      }
    }
  }

  // ---- epilogue: ao[b][s][head*64+dh] bf16 ----
  const int b = bh >> 3, head = bh & 7;
#pragma unroll
  for (int oi = 0; oi < 4; ++oi)
#pragma unroll
    for (int reg = 0; reg < 4; ++reg) {
      int qi = wv * 16 + quad * 4 + reg;
      int s_q = (qh0 + (qi >> 3)) * 64 + qw0 + (qi & 7);
      int dh = oi * 16 + n16;  // oi=(h*2+ntv) -> dh blocks 0,16,32,48
      out[((size_t)(b * 4096 + s_q)) * 512 + head * 64 + dh] =
          (__bf16)O[oi][reg];
    }
}

extern "C" void kernel_launch(void* const* d_in, const int* in_sizes, int n_in,
                              void* d_out, int out_size, void* d_ws,
                              size_t ws_size, hipStream_t stream) {
  const float* x = (const float*)d_in[0];      // [2,64,64,512] fp32
  const float* w_qkv = (const float*)d_in[1];  // [1536,512] fp32
  const float* w_out = (const float*)d_in[2];  // [512,512] fp32
  float* out = (float*)d_out;                  // [2,64,64,512] fp32

  const size_t qelems = (size_t)2 * 8 * 4096 * 64;  // 4,194,304
  __bf16* q = (__bf16*)d_ws;
  __bf16* k = q + qelems;
  __bf16* vt = k + qelems;          // V transposed [bh][dh][s]
  __bf16* xb = vt + qelems;         // converted x; reused as ao
  __bf16* wqb = xb + qelems;        // converted w_qkv
  __bf16* wob = wqb + 1536 * 512;   // converted w_out
  __bf16* ao = xb;                  // attn out aliases xb (x dead after QKV)

  // Stage 0: fused fp32 -> bf16
  cvt_all<<<dim3(5120), dim3(256), 0, stream>>>(x, w_qkv, w_out, xb, wqb, wob);

  // Stage 1: QKV GEMM: 64 i-tiles x 12 e-tiles = 768 blocks (3/CU)
  gemm_lds<true, 128><<<dim3(768), dim3(256), 0, stream>>>(
      xb, wqb, q, k, vt, nullptr, 12);
  // Stage 2: MFMA attention: 1024 workgroups, 45 KB LDS (3 blocks/CU)
  attn_mfma<<<dim3(1024), dim3(256), 0, stream>>>(q, k, vt, ao);
  // Stage 3: out GEMM: 64 i-tiles x 8 e-tiles = 512 blocks
  gemm_lds<false, 64><<<dim3(512), dim3(256), 0, stream>>>(
      ao, wob, nullptr, nullptr, nullptr, out, 8);
}

// Round 14
// 135.540 us; speedup vs baseline: 1.0206x; 1.0206x over previous
//
#include <hip/hip_runtime.h>
#include <hip/hip_bf16.h>

// NeighbourhoodAttnBlock: B=2, H=W=64, D=512, NH=8, DH=64, KERNEL=7
// Inputs fp32; output fp32. Internal pipeline bf16 MFMA.
// Best-known config (R12 lock-in):
// Stage 0: fused convert x, w_qkv, w_out fp32 -> bf16 (1 launch, x8 vec)
// Stage 1: qkv GEMM (BK=64 dual-half LDS staging) -> q,k [bh][s][dh]; vt
// Stage 2: MFMA neighbourhood attention (one-shot K window + V window LDS)
// Stage 3: out GEMM (BK=64, BN=64) -> d_out (fp32)

typedef __bf16 bf16x8 __attribute__((ext_vector_type(8)));
typedef __bf16 bf16x4 __attribute__((ext_vector_type(4)));
typedef float  f32x4  __attribute__((ext_vector_type(4)));

__global__ __launch_bounds__(256) void cvt_all(
    const float* __restrict__ x, const float* __restrict__ wq,
    const float* __restrict__ wo, __bf16* __restrict__ xb,
    __bf16* __restrict__ wqb, __bf16* __restrict__ wob) {
  // 655360 chunks of 2x f32x4 (32B read / 16B write per thread)
  int i = blockIdx.x * 256 + threadIdx.x;
  const float* src;
  __bf16* dst;
  int j = i;
  if (j < 524288) {
    src = x; dst = xb;
  } else if (j < 524288 + 98304) {
    j -= 524288; src = wq; dst = wqb;
  } else {
    j -= 524288 + 98304; src = wo; dst = wob;
  }
  f32x4 v0 = ((const f32x4*)src)[j * 2];
  f32x4 v1 = ((const f32x4*)src)[j * 2 + 1];
  bf16x8 o;
  o[0] = (__bf16)v0[0]; o[1] = (__bf16)v0[1];
  o[2] = (__bf16)v0[2]; o[3] = (__bf16)v0[3];
  o[4] = (__bf16)v1[0]; o[5] = (__bf16)v1[1];
  o[6] = (__bf16)v1[2]; o[7] = (__bf16)v1[3];
  ((bf16x8*)dst)[j] = o;
}

__device__ __forceinline__ void gload_lds16(const __bf16* g, __bf16* l) {
  __builtin_amdgcn_global_load_lds(
      (const __attribute__((address_space(1))) void*)g,
      (__attribute__((address_space(3))) void*)l, 16, 0, 0);
}

// C[i][e] = sum_d A[i][d] * W[e][d];  A:[M,512], W:[E,512] row-major bf16.
// 128xBN block tile, 4 waves x (64 x BN/2). BK=64 via two contiguous 32-col
// half-buffers (global_load_lds needs unpadded contiguity).
template <bool QKV, int BN>
__global__ __launch_bounds__(256, 3) void gemm_lds(
    const __bf16* __restrict__ A, const __bf16* __restrict__ W,
    __bf16* __restrict__ qo, __bf16* __restrict__ ko, __bf16* __restrict__ vo,
    float* __restrict__ co, int etiles) {
  constexpr int K = 512;
  constexpr int NT = BN / 32;
  constexpr int WHALF = BN * 32;
  __shared__ alignas(16) __bf16 Al[2 * 128 * 32];
  __shared__ alignas(16) __bf16 Wl[2 * WHALF];
  const int tid = threadIdx.x;
  const int wv = tid >> 6, lane = tid & 63;
  const int n16 = lane & 15, quad = lane >> 4;
  const int bi = blockIdx.x / etiles, be = blockIdx.x % etiles;
  const int i0 = bi << 7, e0 = be * BN;
  const int wm = (wv & 1) << 6, we = (wv >> 1) * (BN / 2);

  const int srow = (wv << 4) + (lane >> 2);
  const int scol = (lane & 3) << 3;
  const __bf16* gA = A + (size_t)(i0 + srow) * K + scol;
  const __bf16* gW = W + (size_t)(e0 + srow) * K + scol;
  const int soff = (wv << 9) + (lane << 3);

  f32x4 acc[4][NT];
#pragma unroll
  for (int a = 0; a < 4; ++a)
#pragma unroll
    for (int b = 0; b < NT; ++b) acc[a][b] = (f32x4){0.f, 0.f, 0.f, 0.f};

  for (int k0 = 0; k0 < K; k0 += 64) {
    if (k0) __syncthreads();
#pragma unroll
    for (int h = 0; h < 2; ++h) {
      gload_lds16(gA + k0 + h * 32, &Al[h * 4096 + soff]);
      gload_lds16(gA + (size_t)64 * K + k0 + h * 32,
                  &Al[h * 4096 + 64 * 32 + soff]);
      gload_lds16(gW + k0 + h * 32, &Wl[h * WHALF + soff]);
      if (BN == 128)
        gload_lds16(gW + (size_t)64 * K + k0 + h * 32,
                    &Wl[h * WHALF + 64 * 32 + soff]);
    }
    __syncthreads();

#pragma unroll
    for (int h = 0; h < 2; ++h) {
      bf16x8 af[4], wf[NT];
#pragma unroll
      for (int t = 0; t < 4; ++t)
        af[t] = *(const bf16x8*)&Al[h * 4096 + (wm + t * 16 + n16) * 32 +
                                    quad * 8];
#pragma unroll
      for (int t = 0; t < NT; ++t)
        wf[t] = *(const bf16x8*)&Wl[h * WHALF + (we + t * 16 + n16) * 32 +
                                    quad * 8];
#pragma unroll
      for (int mt = 0; mt < 4; ++mt)
#pragma unroll
        for (int nt = 0; nt < NT; ++nt)
          acc[mt][nt] = __builtin_amdgcn_mfma_f32_16x16x32_bf16(
              af[mt], wf[nt], acc[mt][nt], 0, 0, 0);
    }
  }

#pragma unroll
  for (int mt = 0; mt < 4; ++mt)
#pragma unroll
    for (int nt = 0; nt < NT; ++nt) {
      f32x4 f = acc[mt][nt];
      int e = e0 + we + nt * 16 + n16;
#pragma unroll
      for (int rg = 0; rg < 4; ++rg) {
        int i = i0 + wm + mt * 16 + quad * 4 + rg;
        float val = f[rg];
        if (QKV) {
          int t = e >> 9, head = (e >> 6) & 7, dh = e & 63;
          int b = i >> 12, s = i & 4095;
          int bh = b * 8 + head;
          if (t == 2) {
            vo[((size_t)bh * 64 + dh) * 4096 + s] = (__bf16)val;  // vt[bh][dh][s]
          } else {
            size_t off = (((size_t)bh * 4096) + s) * 64 + dh;
            ((t == 0) ? qo : ko)[off] = (__bf16)val;
          }
        } else {
          co[(size_t)i * 512 + e] = val;  // fp32 output
        }
      }
    }
}

// MFMA neighbourhood attention (R7/R12 one-shot config, best known).
// One workgroup per (bh, 8x8 query tile). Phase 1: coop-load full K-window
// (14x16 keys x 64 dh, xor-swizzled) into r1; QK^T via ds_read_b128;
// softmax in regs; P -> per-wave sbuf. Phase 2: barrier; coop-load V-window
// into r1 as vwin[dh][232]; PV fully from LDS.
__global__ __launch_bounds__(256) void attn_mfma(
    const __bf16* __restrict__ q, const __bf16* __restrict__ k,
    const __bf16* __restrict__ vt, __bf16* __restrict__ out) {
  __shared__ alignas(16) __bf16 r1[14848];         // kwin / vwin[64][232]
  __shared__ alignas(16) __bf16 sbuf[4][16][232];  // per-wave P (padded)
  const int tid = threadIdx.x;
  const int wv = tid >> 6;
  const int lane = tid & 63;
  const int n16 = lane & 15, quad = lane >> 4;
  const int bh = blockIdx.x >> 6;
  const int tile = blockIdx.x & 63;
  const int qh0 = (tile >> 3) << 3, qw0 = (tile & 7) << 3;
  int wh0 = qh0 - 3; wh0 = wh0 < 0 ? 0 : (wh0 > 50 ? 50 : wh0);
  int wc0 = qw0 - 3; wc0 = wc0 < 0 ? 0 : (wc0 > 48 ? 48 : wc0);
  wc0 &= ~1;  // -> multiple of 4; window covers [qw0-3, qw0+10]
  const size_t base = (size_t)bh * 4096 * 64;

  // ---- Q A-frags (issue first; fly during coop K load) ----
  const int qi_a = wv * 16 + n16;
  const int sqa = (qh0 + (qi_a >> 3)) * 64 + qw0 + (qi_a & 7);
  const __bf16* qp = q + base + (size_t)sqa * 64 + quad * 8;
  bf16x8 aq0 = *(const bf16x8*)qp;
  bf16x8 aq1 = *(const bf16x8*)(qp + 32);

  // ---- coop load K window: 14 rows x 2 KB contiguous each ----
  const __bf16* kbase = k + base;
#pragma unroll
  for (int i = 0; i < 7; ++i) {
    int ch = i * 256 + tid;           // 1792 16-B chunks
    int kr = ch >> 7, wi = ch & 127;
    int kc = wi >> 3, dh8 = wi & 7;
    bf16x8 d = *(const bf16x8*)(kbase +
        (size_t)((wh0 + kr) * 64 + wc0 + kc) * 64 + dh8 * 8);
    *(bf16x8*)&r1[(kr * 16 + kc) * 64 + ((dh8 ^ (kc & 7)) * 8)] = d;
  }
  __syncthreads();

  // ---- scores from LDS ----
  f32x4 S[14];
  const int skw = wc0 + n16;
  const int sw1 = ((quad ^ (n16 & 7)) * 8);
  const int sw2 = (((4 + quad) ^ (n16 & 7)) * 8);
#pragma unroll
  for (int nt = 0; nt < 14; ++nt) {
    int key = nt * 16 + n16;
    bf16x8 b0 = *(const bf16x8*)&r1[key * 64 + sw1];
    bf16x8 b1 = *(const bf16x8*)&r1[key * 64 + sw2];
    f32x4 s = {0.f, 0.f, 0.f, 0.f};
    s = __builtin_amdgcn_mfma_f32_16x16x32_bf16(aq0, b0, s, 0, 0, 0);
    s = __builtin_amdgcn_mfma_f32_16x16x32_bf16(aq1, b1, s, 0, 0, 0);
    S[nt] = s;
  }

  // ---- exact mask + scale + row max ----
  float mx[4] = {-1e30f, -1e30f, -1e30f, -1e30f};
#pragma unroll
  for (int reg = 0; reg < 4; ++reg) {
    int qi = wv * 16 + quad * 4 + reg;
    int qh = qh0 + (qi >> 3), qw = qw0 + (qi & 7);
    int sh = qh - 3; sh = sh < 0 ? 0 : (sh > 57 ? 57 : sh);
    int sw = qw - 3; sw = sw < 0 ? 0 : (sw > 57 ? 57 : sw);
    bool wok = (skw >= sw) && (skw < sw + 7);
#pragma unroll
    for (int nt = 0; nt < 14; ++nt) {
      int kh = wh0 + nt;
      bool ok = wok && (kh >= sh) && (kh < sh + 7);
      float val = ok ? S[nt][reg] * 0.125f : -1e30f;
      S[nt][reg] = val;
      mx[reg] = mx[reg] > val ? mx[reg] : val;
    }
  }
#pragma unroll
  for (int reg = 0; reg < 4; ++reg)
#pragma unroll
    for (int off = 8; off >= 1; off >>= 1) {
      float o = __shfl_xor(mx[reg], off);
      mx[reg] = mx[reg] > o ? mx[reg] : o;
    }

  // ---- exp + row sum ----
  float sm[4] = {0.f, 0.f, 0.f, 0.f};
#pragma unroll
  for (int nt = 0; nt < 14; ++nt)
#pragma unroll
    for (int reg = 0; reg < 4; ++reg) {
      float p = __expf(S[nt][reg] - mx[reg]);
      S[nt][reg] = p;
      sm[reg] += p;
    }
#pragma unroll
  for (int reg = 0; reg < 4; ++reg)
#pragma unroll
    for (int off = 8; off >= 1; off >>= 1) sm[reg] += __shfl_xor(sm[reg], off);

  // ---- P -> per-wave LDS region (wave-private; no barrier needed) ----
#pragma unroll
  for (int reg = 0; reg < 4; ++reg) {
    float inv = 1.f / sm[reg];
    int row = quad * 4 + reg;
#pragma unroll
    for (int nt = 0; nt < 14; ++nt)
      sbuf[wv][row][nt * 16 + n16] = (__bf16)(S[nt][reg] * inv);
  }

  __syncthreads();  // all waves done reading kwin
  // ---- coop load V window into vwin[dh][232] (key = kr*16+kc) ----
  const __bf16* vtb = vt + base;
#pragma unroll
  for (int i = 0; i < 7; ++i) {
    int c = i * 256 + tid;  // 1792 16-B chunks: c = dh*28 + kr*2 + half
    int dh = c / 28, rem = c % 28;
    int kr = rem >> 1, half = rem & 1;
    bf16x8 d = *(const bf16x8*)(vtb + (size_t)dh * 4096 +
                                (wh0 + kr) * 64 + wc0 + half * 8);
    *(bf16x8*)&r1[dh * 232 + kr * 16 + half * 8] = d;
  }
  __syncthreads();

  // ---- PV: O[16q x 64dh] = P(16x224) . V_win(224x64), all LDS ----
  f32x4 O[4] = {{0.f, 0.f, 0.f, 0.f},
                {0.f, 0.f, 0.f, 0.f},
                {0.f, 0.f, 0.f, 0.f},
                {0.f, 0.f, 0.f, 0.f}};
#pragma unroll
  for (int kt = 0; kt < 7; ++kt) {
    bf16x8 pa = *(const bf16x8*)&sbuf[wv][n16][kt * 32 + quad * 8];
    int key0 = kt * 32 + quad * 8;
#pragma unroll
    for (int ntv = 0; ntv < 4; ++ntv) {
      bf16x8 vb = *(const bf16x8*)&r1[(ntv * 16 + n16) * 232 + key0];
      O[ntv] = __builtin_amdgcn_mfma_f32_16x16x32_bf16(pa, vb, O[ntv], 0, 0, 0);
    }
  }

  // ---- epilogue: ao[b][s][head*64+dh] bf16 ----
  const int b = bh >> 3, head = bh & 7;
#pragma unroll
  for (int ntv = 0; ntv < 4; ++ntv)
#pragma unroll
    for (int reg = 0; reg < 4; ++reg) {
      int qi = wv * 16 + quad * 4 + reg;
      int s_q = (qh0 + (qi >> 3)) * 64 + qw0 + (qi & 7);
      int dh = ntv * 16 + n16;
      out[((size_t)(b * 4096 + s_q)) * 512 + head * 64 + dh] =
          (__bf16)O[ntv][reg];
    }
}

extern "C" void kernel_launch(void* const* d_in, const int* in_sizes, int n_in,
                              void* d_out, int out_size, void* d_ws,
                              size_t ws_size, hipStream_t stream) {
  const float* x = (const float*)d_in[0];      // [2,64,64,512] fp32
  const float* w_qkv = (const float*)d_in[1];  // [1536,512] fp32
  const float* w_out = (const float*)d_in[2];  // [512,512] fp32
  float* out = (float*)d_out;                  // [2,64,64,512] fp32

  const size_t qelems = (size_t)2 * 8 * 4096 * 64;  // 4,194,304
  __bf16* q = (__bf16*)d_ws;
  __bf16* k = q + qelems;
  __bf16* vt = k + qelems;          // V transposed [bh][dh][s]
  __bf16* xb = vt + qelems;         // converted x; reused as ao
  __bf16* wqb = xb + qelems;        // converted w_qkv
  __bf16* wob = wqb + 1536 * 512;   // converted w_out
  __bf16* ao = xb;                  // attn out aliases xb (x dead after QKV)

  // Stage 0: fused fp32 -> bf16 (655360 chunks of 2x f32x4)
  cvt_all<<<dim3(2560), dim3(256), 0, stream>>>(x, w_qkv, w_out, xb, wqb, wob);

  // Stage 1: QKV GEMM: 64 i-tiles x 12 e-tiles = 768 blocks (3/CU)
  gemm_lds<true, 128><<<dim3(768), dim3(256), 0, stream>>>(
      xb, wqb, q, k, vt, nullptr, 12);
  // Stage 2: MFMA attention: 16 bh * 64 tiles = 1024 workgroups
  attn_mfma<<<dim3(1024), dim3(256), 0, stream>>>(q, k, vt, ao);
  // Stage 3: out GEMM: 64 i-tiles x 8 e-tiles = 512 blocks
  gemm_lds<false, 64><<<dim3(512), dim3(256), 0, stream>>>(
      ao, wob, nullptr, nullptr, nullptr, out, 8);
}